// Round 3
// baseline (138.743 us; speedup 1.0000x reference)
//
#include <hip/hip_runtime.h>
#include <math.h>

// DISTANA fused prediction-kernel step.
// B=128, N=4096, IN=9, PRE=4, CELLS=16, OUT=9.
// Outputs concatenated: y (B,N,9) | new_h (B,N,16) | new_cell (B,N,16), f32.
//
// R3: 2 nodes/thread (grid 1024, 512 nodes/block) for 2x memory-level
// parallelism — R2 was latency-bound (VALUBusy 15%, HBM 50%, occ 32%).

#define NB 128
#define NN 4096
#define NNODES (NB * NN)     // 524288
#define IN_DIM 9
#define PRE_DIM 4
#define CELLS 16
#define OUT_DIM 9
#define TPB 256
#define NPT 2                // nodes per thread
#define NPB (TPB * NPT)      // 512 nodes per block
#define XTILE_F4 (NPB * IN_DIM / 4)   // 1152 float4 per x/y tile

__device__ __forceinline__ float fast_rcp(float x) {
    return __builtin_amdgcn_rcpf(x);
}

__device__ __forceinline__ float fast_tanh(float x) {
    x = fminf(fmaxf(x, -15.f), 15.f);
    float e = __expf(2.f * x);
    return (e - 1.f) * fast_rcp(e + 1.f);
}

__global__ __launch_bounds__(TPB, 4) void distana_step_kernel(
    const float* __restrict__ input,      // (B,N,9)
    const float* __restrict__ w_pre,      // (9,4)
    const float* __restrict__ w_lstm,     // (4,16)
    const float* __restrict__ w_post,     // (16,9)
    const float* __restrict__ old_h,      // (B,N,16)
    const float* __restrict__ old_cell,   // (B,N,16)
    float* __restrict__ y,                // (B,N,9)
    float* __restrict__ new_h,            // (B,N,16)
    float* __restrict__ new_cell)         // (B,N,16)
{
    __shared__ float sWpre[IN_DIM * PRE_DIM];    // 36
    __shared__ float sWl[PRE_DIM * CELLS];       // 64
    __shared__ float sWp[CELLS * OUT_DIM];       // 144
    __shared__ float sBuf[NPB * IN_DIM];         // 4608 f (18KB): x tile, then y tile

    const int t = threadIdx.x;
    const int base = blockIdx.x * NPB;

    // ---- issue node-0 h/c loads immediately (independent of everything) ----
    const int idx0 = base + t;
    const float4* hp0 = (const float4*)(old_h    + (size_t)idx0 * CELLS);
    const float4* cp0 = (const float4*)(old_cell + (size_t)idx0 * CELLS);
    float4 h40[4], c40[4];
    #pragma unroll
    for (int q = 0; q < 4; ++q) { h40[q] = hp0[q]; c40[q] = cp0[q]; }

    // ---- stage weights + x tile (coalesced float4) ----
    if (t < IN_DIM * PRE_DIM)  sWpre[t] = w_pre[t];
    if (t < PRE_DIM * CELLS)   sWl[t]   = w_lstm[t];
    if (t < CELLS * OUT_DIM)   sWp[t]   = w_post[t];

    const float4* gin4 = (const float4*)(input + (size_t)base * IN_DIM);
    float4* s4 = (float4*)sBuf;
    #pragma unroll
    for (int i = 0; i < 5; ++i) {
        int j = t + i * TPB;
        if (j < XTILE_F4) s4[j] = gin4[j];
    }

    __syncthreads();

    // ---- pre = tanh(x @ W_pre) for both nodes (x stride 9: conflict-free) ----
    float pre[NPT][PRE_DIM];
    #pragma unroll
    for (int k = 0; k < NPT; ++k) {
        const float* xk = &sBuf[(t + k * TPB) * IN_DIM];
        float x[IN_DIM];
        #pragma unroll
        for (int i = 0; i < IN_DIM; ++i) x[i] = xk[i];
        #pragma unroll
        for (int p = 0; p < PRE_DIM; ++p) {
            float s = 0.f;
            #pragma unroll
            for (int i = 0; i < IN_DIM; ++i)
                s = fmaf(x[i], sWpre[i * PRE_DIM + p], s);
            pre[k][p] = fast_tanh(s);
        }
    }

    __syncthreads();   // x tile dead everywhere -> sBuf reusable for y

    // ---- CIFG cell for both nodes; consume h/c float4-wise to cap liveness ----
    float nh[NPT][CELLS];
    #pragma unroll
    for (int k = 0; k < NPT; ++k) {
        const int idx = base + t + k * TPB;
        const float4* hp = (const float4*)(old_h    + (size_t)idx * CELLS);
        const float4* cp = (const float4*)(old_cell + (size_t)idx * CELLS);
        float4* nhp = (float4*)(new_h    + (size_t)idx * CELLS);
        float4* ncp = (float4*)(new_cell + (size_t)idx * CELLS);
        #pragma unroll
        for (int q = 0; q < 4; ++q) {
            float4 h4 = (k == 0) ? h40[q] : hp[q];
            float4 c4 = (k == 0) ? c40[q] : cp[q];
            float hv[4] = {h4.x, h4.y, h4.z, h4.w};
            float cv[4] = {c4.x, c4.y, c4.z, c4.w};
            float nhv[4], ncv4[4];
            #pragma unroll
            for (int j = 0; j < 4; ++j) {
                const int c = q * 4 + j;
                float s = hv[j];
                #pragma unroll
                for (int p = 0; p < PRE_DIM; ++p)
                    s = fmaf(pre[k][p], sWl[p * CELLS + c], s);
                s = fminf(fmaxf(s, -15.f), 15.f);
                float e  = __expf(s);                 // e^net
                float e2 = e * e;                     // e^{2 net}
                float a  = 1.f + e;
                float b  = 1.f + e2;
                float r  = fast_rcp(a * b);           // one rcp, both gates
                float ig = e * b * r;                 // sigmoid(net)
                float g  = (e2 - 1.f) * a * r;        // tanh(net)
                float nc = fmaf(ig, g - cv[j], cv[j]);
                ncv4[j] = nc;
                float th = fast_tanh(nc);
                nhv[j] = th;
                nh[k][c] = th;
            }
            nhp[q] = make_float4(nhv[0], nhv[1], nhv[2], nhv[3]);
            ncp[q] = make_float4(ncv4[0], ncv4[1], ncv4[2], ncv4[3]);
        }
    }

    // ---- y = tanh(new_h @ W_post) into LDS, then coalesced readback ----
    #pragma unroll
    for (int k = 0; k < NPT; ++k) {
        float* yk = &sBuf[(t + k * TPB) * OUT_DIM];
        #pragma unroll
        for (int o = 0; o < OUT_DIM; ++o) {
            float s = 0.f;
            #pragma unroll
            for (int c = 0; c < CELLS; ++c)
                s = fmaf(nh[k][c], sWp[c * OUT_DIM + o], s);
            yk[o] = fast_tanh(s);
        }
    }

    __syncthreads();

    float4* gy4 = (float4*)(y + (size_t)base * OUT_DIM);
    #pragma unroll
    for (int i = 0; i < 5; ++i) {
        int j = t + i * TPB;
        if (j < XTILE_F4) gy4[j] = s4[j];
    }
}

extern "C" void kernel_launch(void* const* d_in, const int* in_sizes, int n_in,
                              void* d_out, int out_size, void* d_ws, size_t ws_size,
                              hipStream_t stream) {
    const float* input    = (const float*)d_in[0];  // (B,N,9,1)
    const float* w_pre    = (const float*)d_in[1];  // (9,4)
    const float* w_lstm   = (const float*)d_in[2];  // (4,16)
    const float* w_post   = (const float*)d_in[3];  // (16,9)
    const float* old_h    = (const float*)d_in[4];  // (B,N,16)
    const float* old_cell = (const float*)d_in[5];  // (B,N,16)

    float* out = (float*)d_out;
    float* yp       = out;                                    // B*N*9
    float* new_h    = out + (size_t)NNODES * OUT_DIM;         // B*N*16
    float* new_cell = new_h + (size_t)NNODES * CELLS;         // B*N*16

    dim3 grid(NNODES / NPB), block(TPB);
    distana_step_kernel<<<grid, block, 0, stream>>>(
        input, w_pre, w_lstm, w_post, old_h, old_cell, yp, new_h, new_cell);
}

// Round 5
// 106.161 us; speedup vs baseline: 1.3069x; 1.3069x over previous
//
#include <hip/hip_runtime.h>
#include <math.h>

// DISTANA fused prediction-kernel step.
// B=128, N=4096, IN=9, PRE=4, CELLS=16, OUT=9.
// Outputs concatenated: y (B,N,9) | new_h (B,N,16) | new_cell (B,N,16), f32.
//
// R5 = R4 with the NT-store type fixed: __builtin_nontemporal_store requires
// a clang vector type, not HIP's float4 class -> use ext_vector_type(4).
// R4 theory: 2 nodes/thread, STAGED liveness (R3 spilled at VGPR=64 cap),
// node-1 h/c loads issued before node-0's cell compute so they overlap it,
// NT stores for all outputs (never re-read).

#define NB 128
#define NN 4096
#define NNODES (NB * NN)     // 524288
#define IN_DIM 9
#define PRE_DIM 4
#define CELLS 16
#define OUT_DIM 9
#define TPB 256
#define NPT 2                // nodes per thread
#define NPB (TPB * NPT)      // 512 nodes per block
#define XTILE_F4 (NPB * IN_DIM / 4)   // 1152 float4 per x/y tile

typedef float f32x4 __attribute__((ext_vector_type(4)));

__device__ __forceinline__ float fast_rcp(float x) {
    return __builtin_amdgcn_rcpf(x);
}

__device__ __forceinline__ float fast_tanh(float x) {
    x = fminf(fmaxf(x, -15.f), 15.f);
    float e = __expf(2.f * x);
    return (e - 1.f) * fast_rcp(e + 1.f);
}

__device__ __forceinline__ f32x4 ld4(const float* p) {
    return *(const f32x4*)p;
}

__device__ __forceinline__ void nt_st4(float* p, f32x4 v) {
    __builtin_nontemporal_store(v, (f32x4*)p);
}

__global__ __launch_bounds__(TPB) void distana_step_kernel(
    const float* __restrict__ input,      // (B,N,9)
    const float* __restrict__ w_pre,      // (9,4)
    const float* __restrict__ w_lstm,     // (4,16)
    const float* __restrict__ w_post,     // (16,9)
    const float* __restrict__ old_h,      // (B,N,16)
    const float* __restrict__ old_cell,   // (B,N,16)
    float* __restrict__ y,                // (B,N,9)
    float* __restrict__ new_h,            // (B,N,16)
    float* __restrict__ new_cell)         // (B,N,16)
{
    __shared__ float sWpre[IN_DIM * PRE_DIM];    // 36
    __shared__ float sWl[PRE_DIM * CELLS];       // 64
    __shared__ float sWp[CELLS * OUT_DIM];       // 144
    __shared__ float sBuf[NPB * IN_DIM];         // 4608 f (18KB): x tile, then y tile

    const int t = threadIdx.x;
    const int base = blockIdx.x * NPB;
    const int idx0 = base + t;
    const int idx1 = base + t + TPB;

    // ---- issue node-0 h/c loads immediately ----
    const float* hp0 = old_h    + (size_t)idx0 * CELLS;
    const float* cp0 = old_cell + (size_t)idx0 * CELLS;
    f32x4 h0[4], c0[4];
    #pragma unroll
    for (int q = 0; q < 4; ++q) { h0[q] = ld4(hp0 + 4*q); c0[q] = ld4(cp0 + 4*q); }

    // ---- stage weights + x tile (coalesced float4) ----
    if (t < IN_DIM * PRE_DIM)  sWpre[t] = w_pre[t];
    if (t < PRE_DIM * CELLS)   sWl[t]   = w_lstm[t];
    if (t < CELLS * OUT_DIM)   sWp[t]   = w_post[t];

    const f32x4* gin4 = (const f32x4*)(input + (size_t)base * IN_DIM);
    f32x4* s4 = (f32x4*)sBuf;
    #pragma unroll
    for (int i = 0; i < 5; ++i) {
        int j = t + i * TPB;
        if (j < XTILE_F4) s4[j] = gin4[j];
    }

    __syncthreads();

    // ---- pre = tanh(x @ W_pre) for both nodes (stride 9: conflict-free) ----
    float pre[NPT][PRE_DIM];
    #pragma unroll
    for (int k = 0; k < NPT; ++k) {
        const float* xk = &sBuf[(t + k * TPB) * IN_DIM];
        float x[IN_DIM];
        #pragma unroll
        for (int i = 0; i < IN_DIM; ++i) x[i] = xk[i];
        #pragma unroll
        for (int p = 0; p < PRE_DIM; ++p) {
            float s = 0.f;
            #pragma unroll
            for (int i = 0; i < IN_DIM; ++i)
                s = fmaf(x[i], sWpre[i * PRE_DIM + p], s);
            pre[k][p] = fast_tanh(s);
        }
    }

    __syncthreads();   // x tile dead everywhere -> sBuf reusable for y

    // ---- issue node-1 h/c loads NOW: they overlap node-0's cell/y compute ----
    const float* hp1 = old_h    + (size_t)idx1 * CELLS;
    const float* cp1 = old_cell + (size_t)idx1 * CELLS;
    f32x4 h1[4], c1[4];
    #pragma unroll
    for (int q = 0; q < 4; ++q) { h1[q] = ld4(hp1 + 4*q); c1[q] = ld4(cp1 + 4*q); }

    // ==== node 0: cell -> NT stores -> y into LDS (node-0 state dies here) ====
    {
        float nh0[CELLS];
        float* nhp = new_h    + (size_t)idx0 * CELLS;
        float* ncp = new_cell + (size_t)idx0 * CELLS;
        #pragma unroll
        for (int q = 0; q < 4; ++q) {
            f32x4 nhv, ncv;
            #pragma unroll
            for (int j = 0; j < 4; ++j) {
                const int c = q * 4 + j;
                float s = h0[q][j];
                #pragma unroll
                for (int p = 0; p < PRE_DIM; ++p)
                    s = fmaf(pre[0][p], sWl[p * CELLS + c], s);
                s = fminf(fmaxf(s, -15.f), 15.f);
                float e  = __expf(s);
                float e2 = e * e;
                float a  = 1.f + e;
                float b  = 1.f + e2;
                float r  = fast_rcp(a * b);
                float ig = e * b * r;                 // sigmoid(net)
                float g  = (e2 - 1.f) * a * r;        // tanh(net)
                float nc = fmaf(ig, g - c0[q][j], c0[q][j]);
                ncv[j] = nc;
                float th = fast_tanh(nc);
                nhv[j] = th;
                nh0[c] = th;
            }
            nt_st4(nhp + 4*q, nhv);
            nt_st4(ncp + 4*q, ncv);
        }
        float* y0 = &sBuf[t * OUT_DIM];
        #pragma unroll
        for (int o = 0; o < OUT_DIM; ++o) {
            float s = 0.f;
            #pragma unroll
            for (int c = 0; c < CELLS; ++c)
                s = fmaf(nh0[c], sWp[c * OUT_DIM + o], s);
            y0[o] = fast_tanh(s);
        }
    }

    // ==== node 1: same, consuming the loads issued above ====
    {
        float nh1[CELLS];
        float* nhp = new_h    + (size_t)idx1 * CELLS;
        float* ncp = new_cell + (size_t)idx1 * CELLS;
        #pragma unroll
        for (int q = 0; q < 4; ++q) {
            f32x4 nhv, ncv;
            #pragma unroll
            for (int j = 0; j < 4; ++j) {
                const int c = q * 4 + j;
                float s = h1[q][j];
                #pragma unroll
                for (int p = 0; p < PRE_DIM; ++p)
                    s = fmaf(pre[1][p], sWl[p * CELLS + c], s);
                s = fminf(fmaxf(s, -15.f), 15.f);
                float e  = __expf(s);
                float e2 = e * e;
                float a  = 1.f + e;
                float b  = 1.f + e2;
                float r  = fast_rcp(a * b);
                float ig = e * b * r;
                float g  = (e2 - 1.f) * a * r;
                float nc = fmaf(ig, g - c1[q][j], c1[q][j]);
                ncv[j] = nc;
                float th = fast_tanh(nc);
                nhv[j] = th;
                nh1[c] = th;
            }
            nt_st4(nhp + 4*q, nhv);
            nt_st4(ncp + 4*q, ncv);
        }
        float* y1 = &sBuf[(t + TPB) * OUT_DIM];
        #pragma unroll
        for (int o = 0; o < OUT_DIM; ++o) {
            float s = 0.f;
            #pragma unroll
            for (int c = 0; c < CELLS; ++c)
                s = fmaf(nh1[c], sWp[c * OUT_DIM + o], s);
            y1[o] = fast_tanh(s);
        }
    }

    __syncthreads();

    // ---- coalesced NT store of the y tile ----
    const f32x4* s4c = (const f32x4*)sBuf;
    f32x4* gy4 = (f32x4*)(y + (size_t)base * OUT_DIM);
    #pragma unroll
    for (int i = 0; i < 5; ++i) {
        int j = t + i * TPB;
        if (j < XTILE_F4) nt_st4((float*)&gy4[j], s4c[j]);
    }
}

extern "C" void kernel_launch(void* const* d_in, const int* in_sizes, int n_in,
                              void* d_out, int out_size, void* d_ws, size_t ws_size,
                              hipStream_t stream) {
    const float* input    = (const float*)d_in[0];  // (B,N,9,1)
    const float* w_pre    = (const float*)d_in[1];  // (9,4)
    const float* w_lstm   = (const float*)d_in[2];  // (4,16)
    const float* w_post   = (const float*)d_in[3];  // (16,9)
    const float* old_h    = (const float*)d_in[4];  // (B,N,16)
    const float* old_cell = (const float*)d_in[5];  // (B,N,16)

    float* out = (float*)d_out;
    float* yp       = out;                                    // B*N*9
    float* new_h    = out + (size_t)NNODES * OUT_DIM;         // B*N*16
    float* new_cell = new_h + (size_t)NNODES * CELLS;         // B*N*16

    dim3 grid(NNODES / NPB), block(TPB);
    distana_step_kernel<<<grid, block, 0, stream>>>(
        input, w_pre, w_lstm, w_post, old_h, old_cell, yp, new_h, new_cell);
}

// Round 6
// 44.605 us; speedup vs baseline: 3.1105x; 2.3800x over previous
//
#include <hip/hip_runtime.h>
#include <math.h>

// DISTANA fused prediction-kernel step.
// B=128, N=4096, IN=9, PRE=4, CELLS=16, OUT=9.
// Outputs concatenated: y (B,N,9) | new_h (B,N,16) | new_cell (B,N,16), f32.
//
// R6 = R2 structure (1 node/thread, 52 VGPR, no per-thread multi-node state —
// R3/R5 proved 2 nodes/thread spills) with three changes:
//  1. TPB 512 (residency probe: is per-CU block count the occupancy cap?)
//  2. middle barrier removed (thread t's y LDS region == its own x region)
//  3. bijective XCD-aware block swizzle (contiguous stream range per XCD)

#define NB 128
#define NN 4096
#define NNODES (NB * NN)     // 524288
#define IN_DIM 9
#define PRE_DIM 4
#define CELLS 16
#define OUT_DIM 9
#define TPB 512
#define NPB TPB              // 1 node per thread
#define NBLK (NNODES / NPB)  // 1024 blocks
#define NXCD 8
#define XTILE_F4 (NPB * IN_DIM / 4)   // 1152 float4 per x/y tile

typedef float f32x4 __attribute__((ext_vector_type(4)));

__device__ __forceinline__ float fast_rcp(float x) {
    return __builtin_amdgcn_rcpf(x);
}

__device__ __forceinline__ float fast_tanh(float x) {
    x = fminf(fmaxf(x, -15.f), 15.f);
    float e = __expf(2.f * x);
    return (e - 1.f) * fast_rcp(e + 1.f);
}

__device__ __forceinline__ f32x4 ld4(const float* p) {
    return *(const f32x4*)p;
}

__global__ __launch_bounds__(TPB) void distana_step_kernel(
    const float* __restrict__ input,      // (B,N,9)
    const float* __restrict__ w_pre,      // (9,4)
    const float* __restrict__ w_lstm,     // (4,16)
    const float* __restrict__ w_post,     // (16,9)
    const float* __restrict__ old_h,      // (B,N,16)
    const float* __restrict__ old_cell,   // (B,N,16)
    float* __restrict__ y,                // (B,N,9)
    float* __restrict__ new_h,            // (B,N,16)
    float* __restrict__ new_cell)         // (B,N,16)
{
    __shared__ float sWpre[IN_DIM * PRE_DIM];    // 36
    __shared__ float sWl[PRE_DIM * CELLS];       // 64
    __shared__ float sWp[CELLS * OUT_DIM];       // 144
    __shared__ float sBuf[NPB * IN_DIM];         // 4608 f (18KB): x tile, then y tile

    // bijective XCD swizzle: consecutive dispatch ids round-robin XCDs;
    // map so each XCD owns a contiguous range of tiles. 1024 % 8 == 0.
    const int bid = blockIdx.x;
    const int swz = (bid & (NXCD - 1)) * (NBLK / NXCD) + (bid >> 3);

    const int t = threadIdx.x;
    const int base = swz * NPB;
    const int idx = base + t;

    // ---- issue h/c loads immediately (deepest dependency) ----
    const float* hp = old_h    + (size_t)idx * CELLS;
    const float* cp = old_cell + (size_t)idx * CELLS;
    f32x4 h[4], c[4];
    #pragma unroll
    for (int q = 0; q < 4; ++q) { h[q] = ld4(hp + 4*q); c[q] = ld4(cp + 4*q); }

    // ---- stage weights + x tile (coalesced float4) ----
    if (t < IN_DIM * PRE_DIM)  sWpre[t] = w_pre[t];
    if (t < PRE_DIM * CELLS)   sWl[t]   = w_lstm[t];
    if (t < CELLS * OUT_DIM)   sWp[t]   = w_post[t];

    const f32x4* gin4 = (const f32x4*)(input + (size_t)base * IN_DIM);
    f32x4* s4 = (f32x4*)sBuf;
    #pragma unroll
    for (int i = 0; i < 3; ++i) {
        int j = t + i * TPB;
        if (j < XTILE_F4) s4[j] = gin4[j];
    }

    __syncthreads();   // barrier #1: x tile + weights visible

    // ---- pre = tanh(x @ W_pre)  (stride 9 -> 2-way bank alias, free) ----
    const float* xk = &sBuf[t * IN_DIM];
    float x[IN_DIM];
    #pragma unroll
    for (int i = 0; i < IN_DIM; ++i) x[i] = xk[i];

    float pre[PRE_DIM];
    #pragma unroll
    for (int p = 0; p < PRE_DIM; ++p) {
        float s = 0.f;
        #pragma unroll
        for (int i = 0; i < IN_DIM; ++i)
            s = fmaf(x[i], sWpre[i * PRE_DIM + p], s);
        pre[p] = fast_tanh(s);
    }

    // NO barrier here: thread t's x region [t*9, t*9+9) is the same region it
    // will overwrite with y below — per-thread private, no cross-thread hazard.

    // ---- CIFG cell: one exp + one rcp for BOTH gates per cell ----
    float nh[CELLS];
    float* nhp = new_h    + (size_t)idx * CELLS;
    float* ncp = new_cell + (size_t)idx * CELLS;
    #pragma unroll
    for (int q = 0; q < 4; ++q) {
        f32x4 nhv, ncv;
        #pragma unroll
        for (int j = 0; j < 4; ++j) {
            const int cc = q * 4 + j;
            float s = h[q][j];
            #pragma unroll
            for (int p = 0; p < PRE_DIM; ++p)
                s = fmaf(pre[p], sWl[p * CELLS + cc], s);
            s = fminf(fmaxf(s, -15.f), 15.f);
            float e  = __expf(s);                 // e^net
            float e2 = e * e;                     // e^{2 net}
            float a  = 1.f + e;
            float b  = 1.f + e2;
            float r  = fast_rcp(a * b);           // one rcp, both gates
            float ig = e * b * r;                 // sigmoid(net)
            float g  = (e2 - 1.f) * a * r;        // tanh(net)
            float nc = fmaf(ig, g - c[q][j], c[q][j]);
            ncv[j] = nc;
            float th = fast_tanh(nc);
            nhv[j] = th;
            nh[cc] = th;
        }
        *(f32x4*)(nhp + 4*q) = nhv;
        *(f32x4*)(ncp + 4*q) = ncv;
    }

    // ---- y = tanh(new_h @ W_post) into own LDS region ----
    float* yk = &sBuf[t * OUT_DIM];
    #pragma unroll
    for (int o = 0; o < OUT_DIM; ++o) {
        float s = 0.f;
        #pragma unroll
        for (int cc = 0; cc < CELLS; ++cc)
            s = fmaf(nh[cc], sWp[cc * OUT_DIM + o], s);
        yk[o] = fast_tanh(s);
    }

    __syncthreads();   // barrier #2: y tile complete

    // ---- coalesced float4 store of the y tile ----
    f32x4* gy4 = (f32x4*)(y + (size_t)base * OUT_DIM);
    #pragma unroll
    for (int i = 0; i < 3; ++i) {
        int j = t + i * TPB;
        if (j < XTILE_F4) gy4[j] = s4[j];
    }
}

extern "C" void kernel_launch(void* const* d_in, const int* in_sizes, int n_in,
                              void* d_out, int out_size, void* d_ws, size_t ws_size,
                              hipStream_t stream) {
    const float* input    = (const float*)d_in[0];  // (B,N,9,1)
    const float* w_pre    = (const float*)d_in[1];  // (9,4)
    const float* w_lstm   = (const float*)d_in[2];  // (4,16)
    const float* w_post   = (const float*)d_in[3];  // (16,9)
    const float* old_h    = (const float*)d_in[4];  // (B,N,16)
    const float* old_cell = (const float*)d_in[5];  // (B,N,16)

    float* out = (float*)d_out;
    float* yp       = out;                                    // B*N*9
    float* new_h    = out + (size_t)NNODES * OUT_DIM;         // B*N*16
    float* new_cell = new_h + (size_t)NNODES * CELLS;         // B*N*16

    dim3 grid(NBLK), block(TPB);
    distana_step_kernel<<<grid, block, 0, stream>>>(
        input, w_pre, w_lstm, w_post, old_h, old_cell, yp, new_h, new_cell);
}

// Round 7
// 33.380 us; speedup vs baseline: 4.1565x; 1.3363x over previous
//
#include <hip/hip_runtime.h>
#include <math.h>

// DISTANA fused prediction-kernel step.
// B=128, N=4096, IN=9, PRE=4, CELLS=16, OUT=9.
// Outputs: y (B,N,9) | new_h (B,N,16) | new_cell (B,N,16), f32 concat.
//
// R7: quad-cooperative decomposition. 4 lanes per node -> 16 nodes/wave,
// 64 nodes per 256-thread block, grid 8192 (= 4 machine-fills of waves).
// R2-R6 were latency-bound with exactly one wave-fill (occupancy ~36%,
// VALUBusy 14%, HBM ~30%); per-thread ILP (2 nodes/thread) spilled twice
// (R3: VGPR cap, R5: 172 VGPR). This keeps per-lane state tiny and gets
// latency hiding from wave oversubscription instead.
//  - h/c/new_h/new_cell: per-lane aligned float4, wave-contiguous 1KiB
//  - pre/y reductions: quad butterflies via ds_swizzle (xor1, xor2)
//  - weights in LDS (one barrier); x/y scalar dword (36B/node window)

#define NNODES 524288
#define IN_DIM 9
#define CELLS 16
#define OUT_DIM 9
#define TPB 256
#define NPB 64               // nodes per block (4 lanes/node)
#define NBLK (NNODES / NPB)  // 8192, divisible by 8
#define NXCD 8

typedef float f32x4 __attribute__((ext_vector_type(4)));

__device__ __forceinline__ float fast_rcp(float x) {
    return __builtin_amdgcn_rcpf(x);
}

__device__ __forceinline__ float fast_tanh(float x) {
    x = fminf(fmaxf(x, -15.f), 15.f);
    float e = __expf(2.f * x);
    return (e - 1.f) * fast_rcp(e + 1.f);
}

// sum over the 4 lanes of a quad (ds_swizzle BitMode: xor 1 then xor 2)
__device__ __forceinline__ float qsum(float v) {
    v += __int_as_float(__builtin_amdgcn_ds_swizzle(__float_as_int(v), 0x041F));
    v += __int_as_float(__builtin_amdgcn_ds_swizzle(__float_as_int(v), 0x081F));
    return v;
}

__global__ __launch_bounds__(TPB) void distana_quad_kernel(
    const float* __restrict__ input,      // (B,N,9)
    const float* __restrict__ w_pre,      // (9,4)
    const float* __restrict__ w_lstm,     // (4,16)
    const float* __restrict__ w_post,     // (16,9)
    const float* __restrict__ old_h,      // (B,N,16)
    const float* __restrict__ old_cell,   // (B,N,16)
    float* __restrict__ y,                // (B,N,9)
    float* __restrict__ new_h,            // (B,N,16)
    float* __restrict__ new_cell)         // (B,N,16)
{
    __shared__ float sWpre[64];   // (16 rows x 4), rows 9..15 zeroed
    __shared__ float sWl[64];     // (4,16)
    __shared__ float sWp[144];    // (16,9)

    const int t   = threadIdx.x;
    const int bid = blockIdx.x;
    // bijective XCD swizzle: contiguous tile range per XCD (8192 % 8 == 0)
    const int swz  = (bid & (NXCD - 1)) * (NBLK / NXCD) + (bid >> 3);
    const int node = swz * NPB + (t >> 2);
    const int sub  = t & 3;

    // ---- issue global loads first (overlap with weight staging) ----
    const float* hp = old_h    + (size_t)node * CELLS + sub * 4;
    const float* cp = old_cell + (size_t)node * CELLS + sub * 4;
    f32x4 h = *(const f32x4*)hp;          // wave: 16 nodes x 64B contiguous
    f32x4 c = *(const f32x4*)cp;

    const float* xp = input + (size_t)node * IN_DIM;
    f32x4 xl = {0.f, 0.f, 0.f, 0.f};      // this lane's x slice (zero-padded)
    if (sub == 0)      { xl[0] = xp[0]; xl[1] = xp[1]; xl[2] = xp[2]; xl[3] = xp[3]; }
    else if (sub == 1) { xl[0] = xp[4]; xl[1] = xp[5]; xl[2] = xp[6]; xl[3] = xp[7]; }
    else if (sub == 2) { xl[0] = xp[8]; }

    // ---- stage weights in LDS ----
    if (t < 64)  sWpre[t] = (t < 36) ? w_pre[t] : 0.f;
    if (t < 64)  sWl[t]   = w_lstm[t];
    if (t < 144) sWp[t]   = w_post[t];
    __syncthreads();

    // ---- pre = tanh(x @ W_pre): per-lane partial dot + quad butterfly ----
    // lane's rows i = sub*4+k (rows >= 9 are zero-padded in sWpre, xl padded 0)
    float pre[4];
    #pragma unroll
    for (int p = 0; p < 4; ++p) {
        float s = 0.f;
        #pragma unroll
        for (int k = 0; k < 4; ++k)
            s = fmaf(xl[k], sWpre[(sub * 4 + k) * 4 + p], s);
        pre[p] = fast_tanh(qsum(s));
    }

    // ---- CIFG cell: this lane owns cells sub*4 .. sub*4+3 ----
    f32x4 nh, nc;
    #pragma unroll
    for (int j = 0; j < 4; ++j) {
        const int cc = sub * 4 + j;
        float s = h[j];
        #pragma unroll
        for (int p = 0; p < 4; ++p)
            s = fmaf(pre[p], sWl[p * CELLS + cc], s);
        s = fminf(fmaxf(s, -15.f), 15.f);
        float e  = __expf(s);                 // e^net
        float e2 = e * e;                     // e^{2 net}
        float a  = 1.f + e;
        float b  = 1.f + e2;
        float r  = fast_rcp(a * b);           // one rcp for both gates
        float ig = e * b * r;                 // sigmoid(net)
        float g  = (e2 - 1.f) * a * r;        // tanh(net)
        float v  = fmaf(ig, g - c[j], c[j]);  // (1-i)*oc + i*g
        nc[j] = v;
        nh[j] = fast_tanh(v);
    }
    *(f32x4*)(new_h    + (size_t)node * CELLS + sub * 4) = nh;
    *(f32x4*)(new_cell + (size_t)node * CELLS + sub * 4) = nc;

    // ---- y = tanh(new_h @ W_post): partial over own 4 cells + butterfly ----
    float py[OUT_DIM];
    #pragma unroll
    for (int o = 0; o < OUT_DIM; ++o) {
        float s = 0.f;
        #pragma unroll
        for (int j = 0; j < 4; ++j)
            s = fmaf(nh[j], sWp[(sub * 4 + j) * OUT_DIM + o], s);
        py[o] = qsum(s);
    }
    float* yo = y + (size_t)node * OUT_DIM;
    if (sub == 0) {
        yo[0] = fast_tanh(py[0]); yo[1] = fast_tanh(py[1]);
        yo[2] = fast_tanh(py[2]); yo[3] = fast_tanh(py[3]);
    } else if (sub == 1) {
        yo[4] = fast_tanh(py[4]); yo[5] = fast_tanh(py[5]);
        yo[6] = fast_tanh(py[6]); yo[7] = fast_tanh(py[7]);
    } else if (sub == 2) {
        yo[8] = fast_tanh(py[8]);
    }
}

extern "C" void kernel_launch(void* const* d_in, const int* in_sizes, int n_in,
                              void* d_out, int out_size, void* d_ws, size_t ws_size,
                              hipStream_t stream) {
    const float* input    = (const float*)d_in[0];  // (B,N,9,1)
    const float* w_pre    = (const float*)d_in[1];  // (9,4)
    const float* w_lstm   = (const float*)d_in[2];  // (4,16)
    const float* w_post   = (const float*)d_in[3];  // (16,9)
    const float* old_h    = (const float*)d_in[4];  // (B,N,16)
    const float* old_cell = (const float*)d_in[5];  // (B,N,16)

    float* out = (float*)d_out;
    float* yp       = out;                                    // B*N*9
    float* new_h    = out + (size_t)NNODES * OUT_DIM;         // B*N*16
    float* new_cell = new_h + (size_t)NNODES * CELLS;         // B*N*16

    dim3 grid(NBLK), block(TPB);
    distana_quad_kernel<<<grid, block, 0, stream>>>(
        input, w_pre, w_lstm, w_post, old_h, old_cell, yp, new_h, new_cell);
}